// Round 1
// baseline (873.569 us; speedup 1.0000x reference)
//
#include <hip/hip_runtime.h>

#define NN 50000
#define DD 128
#define NE 800000
#define BN_EPS 1e-5f

// ---------------- CSR build ----------------
__global__ void k_hist(const int* __restrict__ dst, int* __restrict__ cnt, int ne) {
    int i = blockIdx.x * blockDim.x + threadIdx.x;
    if (i < ne) atomicAdd(&cnt[dst[i]], 1);
}

__global__ __launch_bounds__(1024) void k_scan(const int* __restrict__ cnt,
                                               int* __restrict__ rowp,
                                               int* __restrict__ cursor,
                                               float* __restrict__ dinv,
                                               int n) {
    __shared__ int tsum[1024];
    int tid = threadIdx.x;
    int chunk = (n + 1023) / 1024;
    int start = tid * chunk;
    int end = min(start + chunk, n);
    int s = 0;
    for (int i = start; i < end; i++) s += cnt[i];
    tsum[tid] = s;
    __syncthreads();
    for (int off = 1; off < 1024; off <<= 1) {
        int add = (tid >= off) ? tsum[tid - off] : 0;
        __syncthreads();
        tsum[tid] += add;
        __syncthreads();
    }
    int excl = (tid == 0) ? 0 : tsum[tid - 1];
    for (int i = start; i < end; i++) {
        rowp[i] = excl;
        cursor[i] = excl;
        dinv[i] = 1.0f / sqrtf((float)(cnt[i] + 1));
        excl += cnt[i];
    }
    if (tid == 1023) rowp[n] = tsum[1023];
}

__global__ void k_scatter(const int* __restrict__ src, const int* __restrict__ dst,
                          int* __restrict__ cursor, int* __restrict__ col,
                          float* __restrict__ val, const float* __restrict__ dinv,
                          int ne) {
    int i = blockIdx.x * blockDim.x + threadIdx.x;
    if (i < ne) {
        int d = dst[i], s = src[i];
        int pos = atomicAdd(&cursor[d], 1);
        col[pos] = s;
        val[pos] = dinv[s];
    }
}

// ---------------- GEMM: C[n,128] = A[n,128] * W[128,128] ----------------
#define GROWS 32
__global__ __launch_bounds__(256) void k_gemm(const float* __restrict__ A,
                                              const float* __restrict__ W,
                                              float* __restrict__ C, int n) {
    __shared__ float sA[GROWS][DD];   // 16 KB
    __shared__ float sW[DD][DD];      // 64 KB
    int tid = threadIdx.x;
    int row0 = blockIdx.x * GROWS;

    // stage W (16384 floats, 16 float4 per thread)
    {
        const float4* Wv = (const float4*)W;
        float4* sWv = (float4*)&sW[0][0];
        for (int i = tid; i < DD * DD / 4; i += 256) sWv[i] = Wv[i];
    }
    // stage A tile (4096 floats, 4 float4 per thread)
    {
        const float4* Av = (const float4*)(A + (size_t)row0 * DD);
        float4* sAv = (float4*)&sA[0][0];
        for (int i = tid; i < GROWS * DD / 4; i += 256) {
            int r = i >> 5;  // 32 float4 per row
            float4 v = make_float4(0.f, 0.f, 0.f, 0.f);
            if (row0 + r < n) v = Av[i];
            sAv[i] = v;
        }
    }
    __syncthreads();

    int tx = tid & 31;   // col group: cols tx*4 .. +3
    int ty = tid >> 5;   // row group: rows ty*4 .. +3
    float acc[4][4] = {};
    for (int k = 0; k < DD; k += 4) {
        float a[4][4], b[4][4];
        #pragma unroll
        for (int r = 0; r < 4; r++)
            *(float4*)a[r] = *(const float4*)&sA[ty * 4 + r][k];
        #pragma unroll
        for (int kk = 0; kk < 4; kk++)
            *(float4*)b[kk] = *(const float4*)&sW[k + kk][tx * 4];
        #pragma unroll
        for (int r = 0; r < 4; r++)
            #pragma unroll
            for (int kk = 0; kk < 4; kk++)
                #pragma unroll
                for (int c = 0; c < 4; c++)
                    acc[r][c] += a[r][kk] * b[kk][c];
    }
    #pragma unroll
    for (int r = 0; r < 4; r++) {
        int row = row0 + ty * 4 + r;
        if (row < n)
            *(float4*)(C + (size_t)row * DD + tx * 4) = *(float4*)acc[r];
    }
}

// ---------------- aggregation: one wave per dst node ----------------
__global__ __launch_bounds__(256) void k_agg(const float* __restrict__ h,
                                             const int* __restrict__ rowp,
                                             const int* __restrict__ col,
                                             const float* __restrict__ val,
                                             const float* __restrict__ dinv,
                                             const float* __restrict__ bias,
                                             float* __restrict__ out, int n) {
    int node = blockIdx.x * 4 + (threadIdx.x >> 6);
    if (node >= n) return;
    int lane = threadIdx.x & 63;
    int beg = rowp[node], end = rowp[node + 1];
    float ax = 0.f, ay = 0.f;
    for (int e = beg; e < end; e++) {
        int s = col[e];
        float w = val[e];
        float2 hv = *(const float2*)(h + (size_t)s * DD + lane * 2);
        ax += w * hv.x;
        ay += w * hv.y;
    }
    float di = dinv[node];
    float2 hs = *(const float2*)(h + (size_t)node * DD + lane * 2);
    float2 bv = *(const float2*)(bias + lane * 2);
    float2 o;
    o.x = di * ax + di * di * hs.x + bv.x;
    o.y = di * ay + di * di * hs.y + bv.y;
    *(float2*)(out + (size_t)node * DD + lane * 2) = o;
}

// ---------------- BN stats: per-feature sum & sumsq ----------------
#define SROWS 256
__global__ __launch_bounds__(128) void k_stats(const float* __restrict__ X,
                                               float* __restrict__ sums, int n) {
    int f = threadIdx.x;
    int r0 = blockIdx.x * SROWS;
    int r1 = min(r0 + SROWS, n);
    float s = 0.f, s2 = 0.f;
    for (int r = r0; r < r1; r++) {
        float v = X[(size_t)r * DD + f];
        s += v;
        s2 += v * v;
    }
    atomicAdd(&sums[f], s);
    atomicAdd(&sums[DD + f], s2);
}

// ---------------- BN apply + ReLU + residual ----------------
__global__ __launch_bounds__(256) void k_bn(const float* __restrict__ X,
                                            const float* __restrict__ res,
                                            const float* __restrict__ sums,
                                            const float* __restrict__ gamma,
                                            const float* __restrict__ beta,
                                            float* __restrict__ out, int n) {
    int idx = blockIdx.x * blockDim.x + threadIdx.x;  // one float4
    int total = n * (DD / 4);
    if (idx >= total) return;
    int f = (idx & 31) * 4;
    float4 v = ((const float4*)X)[idx];
    float4 rv = ((const float4*)res)[idx];
    float o[4];
    float vi[4] = {v.x, v.y, v.z, v.w};
    float ri[4] = {rv.x, rv.y, rv.z, rv.w};
    float inv_n = 1.0f / (float)n;
    #pragma unroll
    for (int j = 0; j < 4; j++) {
        float mean = sums[f + j] * inv_n;
        float var = sums[DD + f + j] * inv_n - mean * mean;
        float x = (vi[j] - mean) * (1.0f / sqrtf(var + BN_EPS)) * gamma[f + j] + beta[f + j];
        x = fmaxf(x, 0.f);
        o[j] = x + ri[j];
    }
    ((float4*)out)[idx] = make_float4(o[0], o[1], o[2], o[3]);
}

// ---------------- attention score: e_i = exp(tanh(h_i . Wa + ba)) ----------------
__global__ __launch_bounds__(256) void k_att(const float* __restrict__ H,
                                             const float* __restrict__ Wa,
                                             const float* __restrict__ ba,
                                             float* __restrict__ evec,
                                             float* __restrict__ Z, int n) {
    int node = blockIdx.x * 4 + (threadIdx.x >> 6);
    int lane = threadIdx.x & 63;
    float t = 0.f;
    if (node < n) {
        float2 hv = *(const float2*)(H + (size_t)node * DD + lane * 2);
        float2 wv = *(const float2*)(Wa + lane * 2);
        t = hv.x * wv.x + hv.y * wv.y;
    }
    #pragma unroll
    for (int off = 32; off > 0; off >>= 1) t += __shfl_down(t, off);
    __shared__ float part[4];
    if (lane == 0) {
        float ev = 0.f;
        if (node < n) {
            ev = expf(tanhf(t + ba[0]));
            evec[node] = ev;
        }
        part[threadIdx.x >> 6] = ev;
    }
    __syncthreads();
    if (threadIdx.x == 0) atomicAdd(Z, part[0] + part[1] + part[2] + part[3]);
}

// ---------------- final: out = h * e / Z ----------------
__global__ __launch_bounds__(256) void k_out(const float* __restrict__ H,
                                             const float* __restrict__ evec,
                                             const float* __restrict__ Z,
                                             float* __restrict__ out, int n) {
    int idx = blockIdx.x * blockDim.x + threadIdx.x;
    int total = n * (DD / 4);
    if (idx >= total) return;
    int node = idx >> 5;
    float s = evec[node] / Z[0];
    float4 h = ((const float4*)H)[idx];
    ((float4*)out)[idx] = make_float4(h.x * s, h.y * s, h.z * s, h.w * s);
}

extern "C" void kernel_launch(void* const* d_in, const int* in_sizes, int n_in,
                              void* d_out, int out_size, void* d_ws, size_t ws_size,
                              hipStream_t stream) {
    const float* x   = (const float*)d_in[0];
    const int* eidx  = (const int*)d_in[1];
    const float* W1  = (const float*)d_in[2];
    const float* b1  = (const float*)d_in[3];
    const float* g1  = (const float*)d_in[4];
    const float* be1 = (const float*)d_in[5];
    const float* W2  = (const float*)d_in[6];
    const float* b2  = (const float*)d_in[7];
    const float* g2  = (const float*)d_in[8];
    const float* be2 = (const float*)d_in[9];
    const float* Wa  = (const float*)d_in[10];
    const float* ba  = (const float*)d_in[11];
    float* out = (float*)d_out;

    const int* srcp = eidx;        // edge_index[0]
    const int* dstp = eidx + NE;   // edge_index[1]

    // workspace layout (floats/ints, all chunks 256B-aligned by construction)
    float* bufA = (float*)d_ws;              // N*D
    float* bufB = bufA + (size_t)NN * DD;    // N*D
    float* bufC = bufB + (size_t)NN * DD;    // N*D
    float* val  = bufC + (size_t)NN * DD;    // NE
    float* dinv = val + NE;                  // NN
    float* evec = dinv + NN;                 // NN
    float* sums = evec + NN;                 // 256
    float* Z    = sums + 256;                // 1 (pad 64)
    int* cnt    = (int*)(Z + 64);            // NN
    int* rowp   = cnt + NN;                  // NN+1 (pad to NN+64)
    int* cursor = rowp + NN + 64;            // NN
    int* col    = cursor + NN;               // NE

    // ---- CSR build (once; reused for both layers) ----
    hipMemsetAsync(cnt, 0, (size_t)NN * sizeof(int), stream);
    hipMemsetAsync(Z, 0, sizeof(float), stream);
    k_hist<<<(NE + 255) / 256, 256, 0, stream>>>(dstp, cnt, NE);
    k_scan<<<1, 1024, 0, stream>>>(cnt, rowp, cursor, dinv, NN);
    k_scatter<<<(NE + 255) / 256, 256, 0, stream>>>(srcp, dstp, cursor, col, val, dinv, NE);

    int gemm_grid = (NN + GROWS - 1) / GROWS;
    int agg_grid  = (NN + 3) / 4;
    int stat_grid = (NN + SROWS - 1) / SROWS;
    int ew_grid   = (NN * (DD / 4) + 255) / 256;

    // ---- layer 1 ----
    k_gemm<<<gemm_grid, 256, 0, stream>>>(x, W1, bufA, NN);
    k_agg<<<agg_grid, 256, 0, stream>>>(bufA, rowp, col, val, dinv, b1, bufB, NN);
    hipMemsetAsync(sums, 0, 256 * sizeof(float), stream);
    k_stats<<<stat_grid, 128, 0, stream>>>(bufB, sums, NN);
    k_bn<<<ew_grid, 256, 0, stream>>>(bufB, x, sums, g1, be1, bufC, NN);

    // ---- layer 2 ----
    k_gemm<<<gemm_grid, 256, 0, stream>>>(bufC, W2, bufA, NN);
    k_agg<<<agg_grid, 256, 0, stream>>>(bufA, rowp, col, val, dinv, b2, bufB, NN);
    hipMemsetAsync(sums, 0, 256 * sizeof(float), stream);
    k_stats<<<stat_grid, 128, 0, stream>>>(bufB, sums, NN);
    k_bn<<<ew_grid, 256, 0, stream>>>(bufB, bufC, sums, g2, be2, bufA, NN);  // h2 -> bufA

    // ---- attention + output ----
    k_att<<<agg_grid, 256, 0, stream>>>(bufA, Wa, ba, evec, Z, NN);
    k_out<<<ew_grid, 256, 0, stream>>>(bufA, evec, Z, out, NN);
}

// Round 2
// 624.895 us; speedup vs baseline: 1.3979x; 1.3979x over previous
//
#include <hip/hip_runtime.h>

#define NN 50000
#define DD 128
#define NE 800000
#define BN_EPS 1e-5f

// ---------------- CSR build ----------------
__global__ void k_hist(const int* __restrict__ dst, int* __restrict__ cnt, int ne) {
    int i = blockIdx.x * blockDim.x + threadIdx.x;
    if (i < ne) atomicAdd(&cnt[dst[i]], 1);
}

// phase A: per-block sums of cnt (coalesced)
__global__ __launch_bounds__(256) void k_bsum(const int* __restrict__ cnt,
                                              int* __restrict__ bsum, int n) {
    __shared__ int red[256];
    int i = blockIdx.x * 256 + threadIdx.x;
    int v = (i < n) ? cnt[i] : 0;
    red[threadIdx.x] = v;
    __syncthreads();
    for (int off = 128; off > 0; off >>= 1) {
        if (threadIdx.x < off) red[threadIdx.x] += red[threadIdx.x + off];
        __syncthreads();
    }
    if (threadIdx.x == 0) bsum[blockIdx.x] = red[0];
}

// phase B: inclusive scan of block sums (nb <= 256) in one block
__global__ __launch_bounds__(256) void k_bscan(int* __restrict__ bsum, int nb) {
    __shared__ int sh[256];
    int t = threadIdx.x;
    sh[t] = (t < nb) ? bsum[t] : 0;
    __syncthreads();
    for (int off = 1; off < 256; off <<= 1) {
        int add = (t >= off) ? sh[t - off] : 0;
        __syncthreads();
        sh[t] += add;
        __syncthreads();
    }
    if (t < nb) bsum[t] = sh[t];
}

// phase C: per-block exclusive prefix + write rowp/cursor/dinv (coalesced)
__global__ __launch_bounds__(256) void k_rowp(const int* __restrict__ cnt,
                                              const int* __restrict__ bsum,
                                              int* __restrict__ rowp,
                                              int* __restrict__ cursor,
                                              float* __restrict__ dinv, int n) {
    __shared__ int sh[256];
    int t = threadIdx.x;
    int i = blockIdx.x * 256 + t;
    int v = (i < n) ? cnt[i] : 0;
    sh[t] = v;
    __syncthreads();
    for (int off = 1; off < 256; off <<= 1) {
        int add = (t >= off) ? sh[t - off] : 0;
        __syncthreads();
        sh[t] += add;
        __syncthreads();
    }
    int base = (blockIdx.x > 0) ? bsum[blockIdx.x - 1] : 0;
    int excl = base + sh[t] - v;
    if (i < n) {
        rowp[i] = excl;
        cursor[i] = excl;
        dinv[i] = 1.0f / sqrtf((float)(v + 1));
        if (i == n - 1) rowp[n] = excl + v;
    }
}

__global__ void k_scatter(const int* __restrict__ src, const int* __restrict__ dst,
                          int* __restrict__ cursor, int* __restrict__ col,
                          float* __restrict__ val, const float* __restrict__ dinv,
                          int ne) {
    int i = blockIdx.x * blockDim.x + threadIdx.x;
    if (i < ne) {
        int d = dst[i], s = src[i];
        int pos = atomicAdd(&cursor[d], 1);
        col[pos] = s;
        val[pos] = dinv[s];
    }
}

// ---------------- GEMM: C[n,128] = A[n,128] * W[128,128] ----------------
#define GROWS 32
__global__ __launch_bounds__(256) void k_gemm(const float* __restrict__ A,
                                              const float* __restrict__ W,
                                              float* __restrict__ C, int n) {
    __shared__ float sA[GROWS][DD];   // 16 KB
    __shared__ float sW[DD][DD];      // 64 KB
    int tid = threadIdx.x;
    int row0 = blockIdx.x * GROWS;

    {
        const float4* Wv = (const float4*)W;
        float4* sWv = (float4*)&sW[0][0];
        for (int i = tid; i < DD * DD / 4; i += 256) sWv[i] = Wv[i];
    }
    {
        const float4* Av = (const float4*)(A + (size_t)row0 * DD);
        float4* sAv = (float4*)&sA[0][0];
        for (int i = tid; i < GROWS * DD / 4; i += 256) {
            int r = i >> 5;
            float4 v = make_float4(0.f, 0.f, 0.f, 0.f);
            if (row0 + r < n) v = Av[i];
            sAv[i] = v;
        }
    }
    __syncthreads();

    int tx = tid & 31;
    int ty = tid >> 5;
    float acc[4][4] = {};
    for (int k = 0; k < DD; k += 4) {
        float a[4][4], b[4][4];
        #pragma unroll
        for (int r = 0; r < 4; r++)
            *(float4*)a[r] = *(const float4*)&sA[ty * 4 + r][k];
        #pragma unroll
        for (int kk = 0; kk < 4; kk++)
            *(float4*)b[kk] = *(const float4*)&sW[k + kk][tx * 4];
        #pragma unroll
        for (int r = 0; r < 4; r++)
            #pragma unroll
            for (int kk = 0; kk < 4; kk++)
                #pragma unroll
                for (int c = 0; c < 4; c++)
                    acc[r][c] += a[r][kk] * b[kk][c];
    }
    #pragma unroll
    for (int r = 0; r < 4; r++) {
        int row = row0 + ty * 4 + r;
        if (row < n)
            *(float4*)(C + (size_t)row * DD + tx * 4) = *(float4*)acc[r];
    }
}

// ---------------- aggregation: one wave per dst node ----------------
__global__ __launch_bounds__(256) void k_agg(const float* __restrict__ h,
                                             const int* __restrict__ rowp,
                                             const int* __restrict__ col,
                                             const float* __restrict__ val,
                                             const float* __restrict__ dinv,
                                             const float* __restrict__ bias,
                                             float* __restrict__ out, int n) {
    int node = blockIdx.x * 4 + (threadIdx.x >> 6);
    if (node >= n) return;
    int lane = threadIdx.x & 63;
    int beg = rowp[node], end = rowp[node + 1];
    float ax = 0.f, ay = 0.f;
    for (int e = beg; e < end; e++) {
        int s = col[e];
        float w = val[e];
        float2 hv = *(const float2*)(h + (size_t)s * DD + lane * 2);
        ax += w * hv.x;
        ay += w * hv.y;
    }
    float di = dinv[node];
    float2 hs = *(const float2*)(h + (size_t)node * DD + lane * 2);
    float2 bv = *(const float2*)(bias + lane * 2);
    float2 o;
    o.x = di * ax + di * di * hs.x + bv.x;
    o.y = di * ay + di * di * hs.y + bv.y;
    *(float2*)(out + (size_t)node * DD + lane * 2) = o;
}

// ---------------- BN stats: per-feature sum & sumsq ----------------
#define SROWS 256
__global__ __launch_bounds__(128) void k_stats(const float* __restrict__ X,
                                               float* __restrict__ sums, int n) {
    int f = threadIdx.x;
    int r0 = blockIdx.x * SROWS;
    int r1 = min(r0 + SROWS, n);
    float s = 0.f, s2 = 0.f;
    for (int r = r0; r < r1; r++) {
        float v = X[(size_t)r * DD + f];
        s += v;
        s2 += v * v;
    }
    atomicAdd(&sums[f], s);
    atomicAdd(&sums[DD + f], s2);
}

// ---------------- BN apply + ReLU + residual ----------------
__global__ __launch_bounds__(256) void k_bn(const float* __restrict__ X,
                                            const float* __restrict__ res,
                                            const float* __restrict__ sums,
                                            const float* __restrict__ gamma,
                                            const float* __restrict__ beta,
                                            float* __restrict__ out, int n) {
    int idx = blockIdx.x * blockDim.x + threadIdx.x;
    int total = n * (DD / 4);
    if (idx >= total) return;
    int f = (idx & 31) * 4;
    float4 v = ((const float4*)X)[idx];
    float4 rv = ((const float4*)res)[idx];
    float o[4];
    float vi[4] = {v.x, v.y, v.z, v.w};
    float ri[4] = {rv.x, rv.y, rv.z, rv.w};
    float inv_n = 1.0f / (float)n;
    #pragma unroll
    for (int j = 0; j < 4; j++) {
        float mean = sums[f + j] * inv_n;
        float var = sums[DD + f + j] * inv_n - mean * mean;
        float x = (vi[j] - mean) * (1.0f / sqrtf(var + BN_EPS)) * gamma[f + j] + beta[f + j];
        x = fmaxf(x, 0.f);
        o[j] = x + ri[j];
    }
    ((float4*)out)[idx] = make_float4(o[0], o[1], o[2], o[3]);
}

// ---------------- attention: grid-stride waves, one atomic per block ----------------
#define ATT_BLOCKS 256
__global__ __launch_bounds__(256) void k_att(const float* __restrict__ H,
                                             const float* __restrict__ Wa,
                                             const float* __restrict__ ba,
                                             float* __restrict__ evec,
                                             float* __restrict__ Z, int n) {
    int wave = threadIdx.x >> 6;
    int lane = threadIdx.x & 63;
    int gw = blockIdx.x * 4 + wave;          // global wave id
    int nw = gridDim.x * 4;                  // total waves
    float2 wv = *(const float2*)(Wa + lane * 2);
    float bb = ba[0];
    float lsum = 0.f;
    for (int node = gw; node < n; node += nw) {
        float2 hv = *(const float2*)(H + (size_t)node * DD + lane * 2);
        float t = hv.x * wv.x + hv.y * wv.y;
        #pragma unroll
        for (int off = 1; off < 64; off <<= 1) t += __shfl_xor(t, off);
        float ev = expf(tanhf(t + bb));
        if (lane == 0) {
            evec[node] = ev;
            lsum += ev;
        }
    }
    __shared__ float part[4];
    if (lane == 0) part[wave] = lsum;
    __syncthreads();
    if (threadIdx.x == 0)
        atomicAdd(Z, part[0] + part[1] + part[2] + part[3]);
}

// ---------------- final: out = h * e / Z ----------------
__global__ __launch_bounds__(256) void k_out(const float* __restrict__ H,
                                             const float* __restrict__ evec,
                                             const float* __restrict__ Z,
                                             float* __restrict__ out, int n) {
    int idx = blockIdx.x * blockDim.x + threadIdx.x;
    int total = n * (DD / 4);
    if (idx >= total) return;
    int node = idx >> 5;
    float s = evec[node] / Z[0];
    float4 h = ((const float4*)H)[idx];
    ((float4*)out)[idx] = make_float4(h.x * s, h.y * s, h.z * s, h.w * s);
}

extern "C" void kernel_launch(void* const* d_in, const int* in_sizes, int n_in,
                              void* d_out, int out_size, void* d_ws, size_t ws_size,
                              hipStream_t stream) {
    const float* x   = (const float*)d_in[0];
    const int* eidx  = (const int*)d_in[1];
    const float* W1  = (const float*)d_in[2];
    const float* b1  = (const float*)d_in[3];
    const float* g1  = (const float*)d_in[4];
    const float* be1 = (const float*)d_in[5];
    const float* W2  = (const float*)d_in[6];
    const float* b2  = (const float*)d_in[7];
    const float* g2  = (const float*)d_in[8];
    const float* be2 = (const float*)d_in[9];
    const float* Wa  = (const float*)d_in[10];
    const float* ba  = (const float*)d_in[11];
    float* out = (float*)d_out;

    const int* srcp = eidx;
    const int* dstp = eidx + NE;

    float* bufA = (float*)d_ws;              // N*D
    float* bufB = bufA + (size_t)NN * DD;    // N*D
    float* bufC = bufB + (size_t)NN * DD;    // N*D
    float* val  = bufC + (size_t)NN * DD;    // NE
    float* dinv = val + NE;                  // NN
    float* evec = dinv + NN;                 // NN
    float* sums = evec + NN;                 // 256
    float* Z    = sums + 256;                // 1 (pad 64)
    int* cnt    = (int*)(Z + 64);            // NN
    int* rowp   = cnt + NN;                  // NN+1 (pad 64)
    int* cursor = rowp + NN + 64;            // NN
    int* col    = cursor + NN;               // NE
    int* bsum   = col + NE;                  // 256

    const int nscan = (NN + 255) / 256;      // 196 blocks

    // ---- CSR build ----
    hipMemsetAsync(cnt, 0, (size_t)NN * sizeof(int), stream);
    hipMemsetAsync(Z, 0, sizeof(float), stream);
    k_hist<<<(NE + 255) / 256, 256, 0, stream>>>(dstp, cnt, NE);
    k_bsum<<<nscan, 256, 0, stream>>>(cnt, bsum, NN);
    k_bscan<<<1, 256, 0, stream>>>(bsum, nscan);
    k_rowp<<<nscan, 256, 0, stream>>>(cnt, bsum, rowp, cursor, dinv, NN);
    k_scatter<<<(NE + 255) / 256, 256, 0, stream>>>(srcp, dstp, cursor, col, val, dinv, NE);

    int gemm_grid = (NN + GROWS - 1) / GROWS;
    int agg_grid  = (NN + 3) / 4;
    int stat_grid = (NN + SROWS - 1) / SROWS;
    int ew_grid   = (NN * (DD / 4) + 255) / 256;

    // ---- layer 1 ----
    k_gemm<<<gemm_grid, 256, 0, stream>>>(x, W1, bufA, NN);
    k_agg<<<agg_grid, 256, 0, stream>>>(bufA, rowp, col, val, dinv, b1, bufB, NN);
    hipMemsetAsync(sums, 0, 256 * sizeof(float), stream);
    k_stats<<<stat_grid, 128, 0, stream>>>(bufB, sums, NN);
    k_bn<<<ew_grid, 256, 0, stream>>>(bufB, x, sums, g1, be1, bufC, NN);

    // ---- layer 2 ----
    k_gemm<<<gemm_grid, 256, 0, stream>>>(bufC, W2, bufA, NN);
    k_agg<<<agg_grid, 256, 0, stream>>>(bufA, rowp, col, val, dinv, b2, bufB, NN);
    hipMemsetAsync(sums, 0, 256 * sizeof(float), stream);
    k_stats<<<stat_grid, 128, 0, stream>>>(bufB, sums, NN);
    k_bn<<<ew_grid, 256, 0, stream>>>(bufB, bufC, sums, g2, be2, bufA, NN);

    // ---- attention + output ----
    k_att<<<ATT_BLOCKS, 256, 0, stream>>>(bufA, Wa, ba, evec, Z, NN);
    k_out<<<ew_grid, 256, 0, stream>>>(bufA, evec, Z, out, NN);
}

// Round 3
// 506.913 us; speedup vs baseline: 1.7233x; 1.2327x over previous
//
#include <hip/hip_runtime.h>

#define NN 50000
#define DD 128
#define NE 800000
#define BN_EPS 1e-5f

// ---------------- CSR build ----------------
__global__ void k_hist(const int* __restrict__ dst, int* __restrict__ cnt, int ne) {
    int i = blockIdx.x * blockDim.x + threadIdx.x;
    if (i < ne) atomicAdd(&cnt[dst[i]], 1);
}

// phase A: per-block sums of cnt (coalesced)
__global__ __launch_bounds__(256) void k_bsum(const int* __restrict__ cnt,
                                              int* __restrict__ bsum, int n) {
    __shared__ int red[256];
    int i = blockIdx.x * 256 + threadIdx.x;
    int v = (i < n) ? cnt[i] : 0;
    red[threadIdx.x] = v;
    __syncthreads();
    for (int off = 128; off > 0; off >>= 1) {
        if (threadIdx.x < off) red[threadIdx.x] += red[threadIdx.x + off];
        __syncthreads();
    }
    if (threadIdx.x == 0) bsum[blockIdx.x] = red[0];
}

// phase B: inclusive scan of block sums (nb <= 256) in one block
__global__ __launch_bounds__(256) void k_bscan(int* __restrict__ bsum, int nb) {
    __shared__ int sh[256];
    int t = threadIdx.x;
    sh[t] = (t < nb) ? bsum[t] : 0;
    __syncthreads();
    for (int off = 1; off < 256; off <<= 1) {
        int add = (t >= off) ? sh[t - off] : 0;
        __syncthreads();
        sh[t] += add;
        __syncthreads();
    }
    if (t < nb) bsum[t] = sh[t];
}

// phase C: per-block exclusive prefix + write rowp/cursor/dinv (coalesced)
__global__ __launch_bounds__(256) void k_rowp(const int* __restrict__ cnt,
                                              const int* __restrict__ bsum,
                                              int* __restrict__ rowp,
                                              int* __restrict__ cursor,
                                              float* __restrict__ dinv, int n) {
    __shared__ int sh[256];
    int t = threadIdx.x;
    int i = blockIdx.x * 256 + t;
    int v = (i < n) ? cnt[i] : 0;
    sh[t] = v;
    __syncthreads();
    for (int off = 1; off < 256; off <<= 1) {
        int add = (t >= off) ? sh[t - off] : 0;
        __syncthreads();
        sh[t] += add;
        __syncthreads();
    }
    int base = (blockIdx.x > 0) ? bsum[blockIdx.x - 1] : 0;
    int excl = base + sh[t] - v;
    if (i < n) {
        rowp[i] = excl;
        cursor[i] = excl;
        dinv[i] = 1.0f / sqrtf((float)(v + 1));
        if (i == n - 1) rowp[n] = excl + v;
    }
}

__global__ void k_scatter(const int* __restrict__ src, const int* __restrict__ dst,
                          int* __restrict__ cursor, int* __restrict__ col,
                          float* __restrict__ val, const float* __restrict__ dinv,
                          int ne) {
    int i = blockIdx.x * blockDim.x + threadIdx.x;
    if (i < ne) {
        int d = dst[i], s = src[i];
        int pos = atomicAdd(&cursor[d], 1);
        col[pos] = s;
        val[pos] = dinv[s];
    }
}

// ---------------- GEMM: C[n,128] = A[n,128] * W[128,128] ----------------
#define GROWS 32
__global__ __launch_bounds__(256) void k_gemm(const float* __restrict__ A,
                                              const float* __restrict__ W,
                                              float* __restrict__ C, int n) {
    __shared__ float sA[GROWS][DD];   // 16 KB
    __shared__ float sW[DD][DD];      // 64 KB
    int tid = threadIdx.x;
    int row0 = blockIdx.x * GROWS;

    {
        const float4* Wv = (const float4*)W;
        float4* sWv = (float4*)&sW[0][0];
        for (int i = tid; i < DD * DD / 4; i += 256) sWv[i] = Wv[i];
    }
    {
        const float4* Av = (const float4*)(A + (size_t)row0 * DD);
        float4* sAv = (float4*)&sA[0][0];
        for (int i = tid; i < GROWS * DD / 4; i += 256) {
            int r = i >> 5;
            float4 v = make_float4(0.f, 0.f, 0.f, 0.f);
            if (row0 + r < n) v = Av[i];
            sAv[i] = v;
        }
    }
    __syncthreads();

    int tx = tid & 31;
    int ty = tid >> 5;
    float acc[4][4] = {};
    for (int k = 0; k < DD; k += 4) {
        float a[4][4], b[4][4];
        #pragma unroll
        for (int r = 0; r < 4; r++)
            *(float4*)a[r] = *(const float4*)&sA[ty * 4 + r][k];
        #pragma unroll
        for (int kk = 0; kk < 4; kk++)
            *(float4*)b[kk] = *(const float4*)&sW[k + kk][tx * 4];
        #pragma unroll
        for (int r = 0; r < 4; r++)
            #pragma unroll
            for (int kk = 0; kk < 4; kk++)
                #pragma unroll
                for (int c = 0; c < 4; c++)
                    acc[r][c] += a[r][kk] * b[kk][c];
    }
    #pragma unroll
    for (int r = 0; r < 4; r++) {
        int row = row0 + ty * 4 + r;
        if (row < n)
            *(float4*)(C + (size_t)row * DD + tx * 4) = *(float4*)acc[r];
    }
}

// ---------------- aggregation: one half-wave (32 lanes x float4) per node ----------------
// 2 independent edge-chains per wave + unroll 4 => up to 8 outstanding gathers/wave.
__global__ __launch_bounds__(256) void k_agg(const float* __restrict__ h,
                                             const int* __restrict__ rowp,
                                             const int* __restrict__ col,
                                             const float* __restrict__ val,
                                             const float* __restrict__ dinv,
                                             const float* __restrict__ bias,
                                             float* __restrict__ out, int n) {
    int node = blockIdx.x * 8 + (threadIdx.x >> 5);
    if (node >= n) return;
    int fl = (threadIdx.x & 31) * 4;   // feature offset, 16B per lane
    int beg = rowp[node], end = rowp[node + 1];
    float4 acc = make_float4(0.f, 0.f, 0.f, 0.f);
    #pragma unroll 4
    for (int e = beg; e < end; e++) {
        int s = col[e];
        float w = val[e];
        float4 hv = *(const float4*)(h + (size_t)s * DD + fl);
        acc.x += w * hv.x;
        acc.y += w * hv.y;
        acc.z += w * hv.z;
        acc.w += w * hv.w;
    }
    float di = dinv[node];
    float dii = di * di;
    float4 hs = *(const float4*)(h + (size_t)node * DD + fl);
    float4 bv = *(const float4*)(bias + fl);
    float4 o;
    o.x = di * acc.x + dii * hs.x + bv.x;
    o.y = di * acc.y + dii * hs.y + bv.y;
    o.z = di * acc.z + dii * hs.z + bv.z;
    o.w = di * acc.w + dii * hs.w + bv.w;
    *(float4*)(out + (size_t)node * DD + fl) = o;
}

// ---------------- BN stats: per-feature sum & sumsq ----------------
#define SROWS 64
__global__ __launch_bounds__(128) void k_stats(const float* __restrict__ X,
                                               float* __restrict__ sums, int n) {
    int f = threadIdx.x;
    int r0 = blockIdx.x * SROWS;
    int r1 = min(r0 + SROWS, n);
    float s = 0.f, s2 = 0.f;
    for (int r = r0; r < r1; r++) {
        float v = X[(size_t)r * DD + f];
        s += v;
        s2 += v * v;
    }
    atomicAdd(&sums[f], s);
    atomicAdd(&sums[DD + f], s2);
}

// ---------------- BN apply + ReLU + residual ----------------
__global__ __launch_bounds__(256) void k_bn(const float* __restrict__ X,
                                            const float* __restrict__ res,
                                            const float* __restrict__ sums,
                                            const float* __restrict__ gamma,
                                            const float* __restrict__ beta,
                                            float* __restrict__ out, int n) {
    int idx = blockIdx.x * blockDim.x + threadIdx.x;
    int total = n * (DD / 4);
    if (idx >= total) return;
    int f = (idx & 31) * 4;
    float4 v = ((const float4*)X)[idx];
    float4 rv = ((const float4*)res)[idx];
    float o[4];
    float vi[4] = {v.x, v.y, v.z, v.w};
    float ri[4] = {rv.x, rv.y, rv.z, rv.w};
    float inv_n = 1.0f / (float)n;
    #pragma unroll
    for (int j = 0; j < 4; j++) {
        float mean = sums[f + j] * inv_n;
        float var = sums[DD + f + j] * inv_n - mean * mean;
        float x = (vi[j] - mean) * (1.0f / sqrtf(var + BN_EPS)) * gamma[f + j] + beta[f + j];
        x = fmaxf(x, 0.f);
        o[j] = x + ri[j];
    }
    ((float4*)out)[idx] = make_float4(o[0], o[1], o[2], o[3]);
}

// ---------------- attention: grid-stride waves, one atomic per block ----------------
#define ATT_BLOCKS 256
__global__ __launch_bounds__(256) void k_att(const float* __restrict__ H,
                                             const float* __restrict__ Wa,
                                             const float* __restrict__ ba,
                                             float* __restrict__ evec,
                                             float* __restrict__ Z, int n) {
    int wave = threadIdx.x >> 6;
    int lane = threadIdx.x & 63;
    int gw = blockIdx.x * 4 + wave;
    int nw = gridDim.x * 4;
    float2 wv = *(const float2*)(Wa + lane * 2);
    float bb = ba[0];
    float lsum = 0.f;
    for (int node = gw; node < n; node += nw) {
        float2 hv = *(const float2*)(H + (size_t)node * DD + lane * 2);
        float t = hv.x * wv.x + hv.y * wv.y;
        #pragma unroll
        for (int off = 1; off < 64; off <<= 1) t += __shfl_xor(t, off);
        float ev = expf(tanhf(t + bb));
        if (lane == 0) {
            evec[node] = ev;
            lsum += ev;
        }
    }
    __shared__ float part[4];
    if (lane == 0) part[wave] = lsum;
    __syncthreads();
    if (threadIdx.x == 0)
        atomicAdd(Z, part[0] + part[1] + part[2] + part[3]);
}

// ---------------- final: out = h * e / Z ----------------
__global__ __launch_bounds__(256) void k_out(const float* __restrict__ H,
                                             const float* __restrict__ evec,
                                             const float* __restrict__ Z,
                                             float* __restrict__ out, int n) {
    int idx = blockIdx.x * blockDim.x + threadIdx.x;
    int total = n * (DD / 4);
    if (idx >= total) return;
    int node = idx >> 5;
    float s = evec[node] / Z[0];
    float4 h = ((const float4*)H)[idx];
    ((float4*)out)[idx] = make_float4(h.x * s, h.y * s, h.z * s, h.w * s);
}

extern "C" void kernel_launch(void* const* d_in, const int* in_sizes, int n_in,
                              void* d_out, int out_size, void* d_ws, size_t ws_size,
                              hipStream_t stream) {
    const float* x   = (const float*)d_in[0];
    const int* eidx  = (const int*)d_in[1];
    const float* W1  = (const float*)d_in[2];
    const float* b1  = (const float*)d_in[3];
    const float* g1  = (const float*)d_in[4];
    const float* be1 = (const float*)d_in[5];
    const float* W2  = (const float*)d_in[6];
    const float* b2  = (const float*)d_in[7];
    const float* g2  = (const float*)d_in[8];
    const float* be2 = (const float*)d_in[9];
    const float* Wa  = (const float*)d_in[10];
    const float* ba  = (const float*)d_in[11];
    float* out = (float*)d_out;

    const int* srcp = eidx;
    const int* dstp = eidx + NE;

    float* bufA = (float*)d_ws;              // N*D
    float* bufB = bufA + (size_t)NN * DD;    // N*D
    float* bufC = bufB + (size_t)NN * DD;    // N*D
    float* val  = bufC + (size_t)NN * DD;    // NE
    float* dinv = val + NE;                  // NN
    float* evec = dinv + NN;                 // NN
    float* sums = evec + NN;                 // 256
    float* Z    = sums + 256;                // 1 (pad 64)
    int* cnt    = (int*)(Z + 64);            // NN
    int* rowp   = cnt + NN;                  // NN+1 (pad 64)
    int* cursor = rowp + NN + 64;            // NN
    int* col    = cursor + NN;               // NE
    int* bsum   = col + NE;                  // 256

    const int nscan = (NN + 255) / 256;      // 196 blocks

    // ---- CSR build ----
    hipMemsetAsync(cnt, 0, (size_t)NN * sizeof(int), stream);
    hipMemsetAsync(Z, 0, sizeof(float), stream);
    k_hist<<<(NE + 255) / 256, 256, 0, stream>>>(dstp, cnt, NE);
    k_bsum<<<nscan, 256, 0, stream>>>(cnt, bsum, NN);
    k_bscan<<<1, 256, 0, stream>>>(bsum, nscan);
    k_rowp<<<nscan, 256, 0, stream>>>(cnt, bsum, rowp, cursor, dinv, NN);
    k_scatter<<<(NE + 255) / 256, 256, 0, stream>>>(srcp, dstp, cursor, col, val, dinv, NE);

    int gemm_grid = (NN + GROWS - 1) / GROWS;
    int agg_grid  = (NN + 7) / 8;
    int stat_grid = (NN + SROWS - 1) / SROWS;
    int ew_grid   = (NN * (DD / 4) + 255) / 256;

    // ---- layer 1 ----
    k_gemm<<<gemm_grid, 256, 0, stream>>>(x, W1, bufA, NN);
    k_agg<<<agg_grid, 256, 0, stream>>>(bufA, rowp, col, val, dinv, b1, bufB, NN);
    hipMemsetAsync(sums, 0, 256 * sizeof(float), stream);
    k_stats<<<stat_grid, 128, 0, stream>>>(bufB, sums, NN);
    k_bn<<<ew_grid, 256, 0, stream>>>(bufB, x, sums, g1, be1, bufC, NN);

    // ---- layer 2 ----
    k_gemm<<<gemm_grid, 256, 0, stream>>>(bufC, W2, bufA, NN);
    k_agg<<<agg_grid, 256, 0, stream>>>(bufA, rowp, col, val, dinv, b2, bufB, NN);
    hipMemsetAsync(sums, 0, 256 * sizeof(float), stream);
    k_stats<<<stat_grid, 128, 0, stream>>>(bufB, sums, NN);
    k_bn<<<ew_grid, 256, 0, stream>>>(bufB, bufC, sums, g2, be2, bufA, NN);

    // ---- attention + output ----
    k_att<<<ATT_BLOCKS, 256, 0, stream>>>(bufA, Wa, ba, evec, Z, NN);
    k_out<<<ew_grid, 256, 0, stream>>>(bufA, evec, Z, out, NN);
}